// Round 9
// baseline (159.718 us; speedup 1.0000x reference)
//
#include <hip/hip_runtime.h>
#include <hip/hip_bf16.h>

typedef unsigned short u16;
typedef float f32x4v __attribute__((ext_vector_type(4)));
typedef short short8 __attribute__((ext_vector_type(8)));

#define TSEQ 512
#define EMB  1024
#define DI   2048
#define NH   32
#define DS   64
#define PROJ 4256
#define PROJP 4352
#define NCH  16   // chunks
#define LCH  32   // chunk length
#define KSPLIT2 4

__device__ __forceinline__ u16 f2bf(float f) {
    union { __hip_bfloat16 h; u16 u; } cv;
    cv.h = __float2bfloat16(f);
    return cv.u;
}
__device__ __forceinline__ unsigned pack2(float a, float b) {
    return (unsigned)f2bf(a) | ((unsigned)f2bf(b) << 16);
}
__device__ __forceinline__ float silu(float v) { return v / (1.f + expf(-v)); }

// ---------------- transpose + cast f32 (K x N) -> bf16 (Npad x K), zero-pad n >= N
__device__ __forceinline__ void transpose_tile(
        const float* __restrict__ src, u16* __restrict__ dst,
        int K, int N, int n0, int k0, int tid, float tile[64][68]) {
    const int lr = tid >> 4;          // 0..15: k-row within pass
    const int lc = tid & 15;          // float4 index within row
    #pragma unroll
    for (int ps = 0; ps < 4; ++ps) {
        int r = ps * 16 + lr;
        float4 v;
        if (n0 + lc * 4 + 3 < N) {
            v = *(const float4*)&src[(size_t)(k0 + r) * N + n0 + lc * 4];
        } else {
            float t0 = 0.f, t1 = 0.f, t2 = 0.f, t3 = 0.f;
            int nb = n0 + lc * 4;
            if (nb + 0 < N) t0 = src[(size_t)(k0 + r) * N + nb + 0];
            if (nb + 1 < N) t1 = src[(size_t)(k0 + r) * N + nb + 1];
            if (nb + 2 < N) t2 = src[(size_t)(k0 + r) * N + nb + 2];
            if (nb + 3 < N) t3 = src[(size_t)(k0 + r) * N + nb + 3];
            v = make_float4(t0, t1, t2, t3);
        }
        *(float4*)&tile[r][lc * 4] = v;
    }
    __syncthreads();
    const int kk2 = (tid & 31) * 2;   // even k within tile
    const int nr  = tid >> 5;         // 0..7: n-row within pass
    #pragma unroll
    for (int ps = 0; ps < 8; ++ps) {
        int n = ps * 8 + nr;
        unsigned o = (unsigned)f2bf(tile[kk2][n]) | ((unsigned)f2bf(tile[kk2 + 1][n]) << 16);
        *(unsigned*)&dst[(size_t)(n0 + n) * K + k0 + kk2] = o;
    }
}

// fused prep: w_in transpose (0..1087), w_out transpose (1088..1599), rmsnorm (1600..2111)
__global__ __launch_bounds__(256) void k_prep(
        const float* __restrict__ w_in, u16* __restrict__ w_inT,
        const float* __restrict__ w_out, u16* __restrict__ w_outT,
        const float* __restrict__ x, const float* __restrict__ scale,
        u16* __restrict__ xnb) {
    __shared__ float tile[64][68];
    const int b = blockIdx.x;
    const int tid = threadIdx.x;
    if (b < 1088) {
        int bx = b % 68, by = b / 68;
        transpose_tile(w_in, w_inT, 1024, PROJ, bx * 64, by * 64, tid, tile);
    } else if (b < 1600) {
        int b2 = b - 1088;
        int bx = b2 % 16, by = b2 / 16;
        transpose_tile(w_out, w_outT, 2048, 1024, bx * 64, by * 64, tid, tile);
    } else {
        int t = b - 1600;
        const float4* xr = (const float4*)(x + (size_t)t * EMB);
        float4 v = xr[tid];
        float ss = v.x * v.x + v.y * v.y + v.z * v.z + v.w * v.w;
        #pragma unroll
        for (int off = 32; off; off >>= 1) ss += __shfl_xor(ss, off);
        if ((tid & 63) == 0) tile[0][tid >> 6] = ss;
        __syncthreads();
        float tot = tile[0][0] + tile[0][1] + tile[0][2] + tile[0][3];
        float inv = rsqrtf(tot * (1.f / EMB) + 1e-6f);
        float4 s = ((const float4*)scale)[tid];
        uint2 o;
        o.x = pack2(v.x * inv * s.x, v.y * inv * s.y);
        o.y = pack2(v.z * inv * s.z, v.w * inv * s.w);
        ((uint2*)xnb)[(size_t)t * 256 + tid] = o;
    }
}

// ---------------- bf16 MFMA GEMM with register prefetch.
template<int BM, int BN>
__global__ __launch_bounds__(256) void k_gemm(
        const u16* __restrict__ A, int lda,
        const u16* __restrict__ BT, int ldb,
        float* __restrict__ C, int ldc, int Kper) {
    constexpr int WM = BM / 2, WN = BN / 2, FM = WM / 16, FN = WN / 16;
    constexpr int NA = BM * 8 / 256, NB = BN * 8 / 256;
    __shared__ __align__(16) u16 Al[BM][72];
    __shared__ __align__(16) u16 Bl[BN][72];
    const int tid = threadIdx.x;
    const int wid = tid >> 6, lane = tid & 63;
    const int wr = wid >> 1, wc = wid & 1;
    const int ar = lane & 15, kg = lane >> 4;
    const int row0 = blockIdx.y * BM, col0 = blockIdx.x * BN;
    const int kbase = blockIdx.z * Kper;
    const int Mtot = gridDim.y * BM;
    float* Cz = C + (size_t)blockIdx.z * Mtot * ldc;

    short8 ra[NA], rb[NB];
    auto load_stage = [&](int k0) {
        #pragma unroll
        for (int j = 0; j < NA; ++j) {
            int idx = tid + j * 256;
            ra[j] = *(const short8*)(A + (size_t)(row0 + (idx >> 3)) * lda + k0 + (idx & 7) * 8);
        }
        #pragma unroll
        for (int j = 0; j < NB; ++j) {
            int idx = tid + j * 256;
            rb[j] = *(const short8*)(BT + (size_t)(col0 + (idx >> 3)) * ldb + k0 + (idx & 7) * 8);
        }
    };
    auto write_stage = [&]() {
        #pragma unroll
        for (int j = 0; j < NA; ++j) {
            int idx = tid + j * 256;
            *(short8*)&Al[idx >> 3][(idx & 7) * 8] = ra[j];
        }
        #pragma unroll
        for (int j = 0; j < NB; ++j) {
            int idx = tid + j * 256;
            *(short8*)&Bl[idx >> 3][(idx & 7) * 8] = rb[j];
        }
    };

    f32x4v acc[FM][FN] = {};
    const int NT = Kper / 64;
    load_stage(kbase);
    for (int kt = 0; kt < NT; ++kt) {
        write_stage();
        __syncthreads();
        if (kt + 1 < NT) load_stage(kbase + (kt + 1) * 64);
        #pragma unroll
        for (int kk = 0; kk < 2; ++kk) {
            short8 af[FM], bf[FN];
            #pragma unroll
            for (int m = 0; m < FM; ++m)
                af[m] = *(const short8*)&Al[wr * WM + m * 16 + ar][kk * 32 + kg * 8];
            #pragma unroll
            for (int n = 0; n < FN; ++n)
                bf[n] = *(const short8*)&Bl[wc * WN + n * 16 + ar][kk * 32 + kg * 8];
            #pragma unroll
            for (int m = 0; m < FM; ++m)
                #pragma unroll
                for (int n = 0; n < FN; ++n)
                    acc[m][n] = __builtin_amdgcn_mfma_f32_16x16x32_bf16(
                        af[m], bf[n], acc[m][n], 0, 0, 0);
        }
        __syncthreads();
    }
    #pragma unroll
    for (int m = 0; m < FM; ++m)
        #pragma unroll
        for (int n = 0; n < FN; ++n)
            #pragma unroll
            for (int j = 0; j < 4; ++j) {
                int row = row0 + wr * WM + m * 16 + kg * 4 + j;
                int col = col0 + wc * WN + n * 16 + ar;
                Cz[(size_t)row * ldc + col] = acc[m][n][j];
            }
}

// ---------------- gemm2 split-K reduce + residual: out = x + sum_z part[z]
__global__ __launch_bounds__(256) void k_reduce_out(
        const float* __restrict__ part, const float* __restrict__ x,
        float* __restrict__ out) {
    int i = blockIdx.x * 256 + threadIdx.x;
    float4 v = ((const float4*)x)[i];
    #pragma unroll
    for (int z = 0; z < KSPLIT2; ++z) {
        float4 p = ((const float4*)part)[(size_t)z * (TSEQ * EMB / 4) + i];
        v.x += p.x; v.y += p.y; v.z += p.z; v.w += p.w;
    }
    ((float4*)out)[i] = v;
}

// ---------------- scan stage 1: 1024 threads, thread = (p, q) with 4 states.
// Parallel phase precomputes dtx[t][p] (conv+silu+dt); serial loop is
// 4 FMA + 4-term dot + 4 shfl per step, no intra-loop barrier -> 16 waves
// slide independently (4/SIMD) to hide LDS/shfl latency.
__global__ __launch_bounds__(1024) void k_scan1g(
        const float* __restrict__ proj, const float* __restrict__ cw,
        const float* __restrict__ cb, const float* __restrict__ A_log,
        const float* __restrict__ dt_bias,
        float* __restrict__ Sloc, float* __restrict__ Pcum,
        float* __restrict__ yloc) {
    const int c = blockIdx.x, h = blockIdx.y;
    const int tid = threadIdx.x;
    const int q = tid & 15, p = tid >> 4, n0 = q * 4;
    __shared__ __align__(16) float Blds[LCH][64];
    __shared__ __align__(16) float Clds[LCH][64];
    __shared__ __align__(16) float dtxl[LCH][64];
    __shared__ __align__(16) float xt[LCH + 3][64];
    __shared__ float al[LCH], dl[LCH];
    __shared__ float yl[LCH][64];
    for (int i = tid; i < (LCH + 3) * 64; i += 1024) {
        int r = i >> 6, n = i & 63;
        int tt = c * LCH - 3 + r;
        xt[r][n] = (tt >= 0) ? proj[(size_t)tt * PROJP + DI + h * 64 + n] : 0.f;
    }
    for (int i = tid; i < LCH * 64; i += 1024) {
        int t = i >> 6, n = i & 63;
        Blds[t][n] = proj[(size_t)(c * LCH + t) * PROJP + 2 * DI + NH + n];
        Clds[t][n] = proj[(size_t)(c * LCH + t) * PROJP + 2 * DI + NH + DS + n];
    }
    if (tid < LCH) {
        float z = proj[(size_t)(c * LCH + tid) * PROJP + 2 * DI + h] + dt_bias[h];
        float dt = (z > 20.f) ? z : log1pf(expf(z));
        dl[tid] = dt;
        al[tid] = expf(-expf(A_log[h]) * dt);
    }
    __syncthreads();
    // dtx[t][p] = dt[t] * silu(conv(t, p)) -- fully parallel
    for (int i = tid; i < LCH * 64; i += 1024) {
        int t = i >> 6, pp = i & 63;
        int ch = h * 64 + pp;
        float cv = cb[ch]
                 + cw[0 * DI + ch] * xt[t][pp]     + cw[1 * DI + ch] * xt[t + 1][pp]
                 + cw[2 * DI + ch] * xt[t + 2][pp] + cw[3 * DI + ch] * xt[t + 3][pp];
        dtxl[t][pp] = dl[t] * silu(cv);
    }
    if (tid < LCH) {
        float pr = 1.f;
        #pragma unroll
        for (int k = 0; k < LCH; ++k) if (k <= tid) pr *= al[k];
        Pcum[((size_t)(c * 32 + h)) * LCH + tid] = pr;
    }
    __syncthreads();
    float4 s = make_float4(0.f, 0.f, 0.f, 0.f);
    #pragma unroll 4
    for (int t = 0; t < LCH; ++t) {
        float a = al[t];
        float dtx = dtxl[t][p];
        float4 b = *(const float4*)&Blds[t][n0];
        float4 cc = *(const float4*)&Clds[t][n0];
        s.x = a * s.x + dtx * b.x;
        s.y = a * s.y + dtx * b.y;
        s.z = a * s.z + dtx * b.z;
        s.w = a * s.w + dtx * b.w;
        float yp = s.x * cc.x + s.y * cc.y + s.z * cc.z + s.w * cc.w;
        yp += __shfl_xor(yp, 1);
        yp += __shfl_xor(yp, 2);
        yp += __shfl_xor(yp, 4);
        yp += __shfl_xor(yp, 8);
        if (q == 0) yl[t][p] = yp;
    }
    *(float4*)&Sloc[((size_t)(c * 32 + h) * 64 + p) * 64 + n0] = s;
    __syncthreads();
    for (int i = tid; i < LCH * 64; i += 1024) {
        int t = i >> 6, pp = i & 63;
        yloc[(size_t)(c * LCH + t) * DI + h * 64 + pp] = yl[t][pp];
    }
}

// ---------------- scan stage 2: inter-chunk recurrence (tiny, streaming)
__global__ __launch_bounds__(256) void k_scan2(
        const float* __restrict__ Sloc, const float* __restrict__ Pcum,
        float* __restrict__ Sinit) {
    int gid = blockIdx.x * 256 + threadIdx.x;   // < 32*4096
    int h = gid >> 12, rem = gid & 4095;
    float s = 0.f;
    #pragma unroll
    for (int cc = 0; cc < NCH; ++cc) {
        size_t o = (size_t)(cc * 32 + h) * 4096 + rem;
        Sinit[o] = s;
        s = Pcum[((size_t)(cc * 32 + h)) * LCH + (LCH - 1)] * s + Sloc[o];
    }
}

// ---------------- scan stage 3 (fully t-parallel correction):
// y[t] = yloc[t] + P[t] * (C[t] . Sinit); then gate*silu -> bf16 yg.
__global__ __launch_bounds__(256) void k_corr(
        const float* __restrict__ proj, const float* __restrict__ Sinit,
        const float* __restrict__ Pcum, const float* __restrict__ yloc,
        u16* __restrict__ yg) {
    const int c = blockIdx.x, h = blockIdx.y;
    const int tid = threadIdx.x;
    const int q = tid & 3, p = tid >> 2, n0 = q * 16;
    __shared__ __align__(16) float Clds[LCH][64];
    __shared__ __align__(16) float Sl[64][68];
    __shared__ float Pl[LCH];
    __shared__ float yl[LCH][64];
    for (int i = tid; i < LCH * 64; i += 256) {
        int t = i >> 6, n = i & 63;
        Clds[t][n] = proj[(size_t)(c * LCH + t) * PROJP + 2 * DI + NH + DS + n];
    }
    for (int i = tid; i < 4096; i += 256) {
        Sl[i >> 6][i & 63] = Sinit[(size_t)(c * 32 + h) * 4096 + i];
    }
    if (tid < LCH) Pl[tid] = Pcum[((size_t)(c * 32 + h)) * LCH + tid];
    __syncthreads();
    float st[16];
    #pragma unroll
    for (int i4 = 0; i4 < 4; ++i4) {
        float4 v = *(const float4*)&Sl[p][n0 + i4 * 4];
        st[i4*4+0] = v.x; st[i4*4+1] = v.y; st[i4*4+2] = v.z; st[i4*4+3] = v.w;
    }
    for (int t = 0; t < LCH; ++t) {
        const float4* crow = (const float4*)&Clds[t][n0];
        float acc = 0.f;
        #pragma unroll
        for (int i4 = 0; i4 < 4; ++i4) {
            float4 cc4 = crow[i4];
            acc += st[i4*4+0] * cc4.x + st[i4*4+1] * cc4.y
                 + st[i4*4+2] * cc4.z + st[i4*4+3] * cc4.w;
        }
        acc += __shfl_xor(acc, 1);
        acc += __shfl_xor(acc, 2);
        if (q == 0) yl[t][p] = acc * Pl[t];
    }
    __syncthreads();
    for (int i = tid; i < LCH * 64; i += 256) {
        int t = i >> 6, pp = i & 63;
        float y = yloc[(size_t)(c * LCH + t) * DI + h * 64 + pp] + yl[t][pp];
        float g = proj[(size_t)(c * LCH + t) * PROJP + h * 64 + pp];
        yg[(size_t)(c * LCH + t) * DI + h * 64 + pp] = f2bf(y * silu(g));
    }
}

extern "C" void kernel_launch(void* const* d_in, const int* in_sizes, int n_in,
                              void* d_out, int out_size, void* d_ws, size_t ws_size,
                              hipStream_t stream) {
    (void)in_sizes; (void)n_in; (void)out_size; (void)ws_size;
    const float* x       = (const float*)d_in[0];
    const float* nscale  = (const float*)d_in[1];
    const float* w_in    = (const float*)d_in[2];
    const float* conv_w  = (const float*)d_in[3];
    const float* conv_b  = (const float*)d_in[4];
    const float* A_log   = (const float*)d_in[5];
    const float* dt_bias = (const float*)d_in[6];
    const float* w_out   = (const float*)d_in[7];
    float* out = (float*)d_out;

    char* wsp = (char*)d_ws;
    auto alloc = [&](size_t bytes) {
        char* ptr = wsp;
        wsp += (bytes + 255) & ~(size_t)255;
        return ptr;
    };
    u16*   w_inT  = (u16*)  alloc((size_t)PROJP * 1024 * 2);
    u16*   w_outT = (u16*)  alloc((size_t)1024 * 2048 * 2);
    u16*   xnb    = (u16*)  alloc((size_t)512 * 1024 * 2);
    float* proj   = (float*)alloc((size_t)512 * PROJP * 4);
    float* Pcum   = (float*)alloc((size_t)NCH * 32 * LCH * 4);
    float* Sloc   = (float*)alloc((size_t)NCH * 32 * 4096 * 4);
    float* Sinit  = (float*)alloc((size_t)NCH * 32 * 4096 * 4);
    float* yloc   = (float*)alloc((size_t)512 * 2048 * 4);
    u16*   yg     = (u16*)  alloc((size_t)512 * 2048 * 2);
    float* part2  = (float*)alloc((size_t)KSPLIT2 * 512 * 1024 * 4);

    k_prep<<<2112, 256, 0, stream>>>(w_in, w_inT, w_out, w_outT, x, nscale, xnb);
    k_gemm<32, 128><<<dim3(34, 16, 1), 256, 0, stream>>>(
        xnb, 1024, w_inT, 1024, proj, PROJP, 1024);
    k_scan1g<<<dim3(NCH, 32), 1024, 0, stream>>>(
        proj, conv_w, conv_b, A_log, dt_bias, Sloc, Pcum, yloc);
    k_scan2<<<512, 256, 0, stream>>>(Sloc, Pcum, Sinit);
    k_corr<<<dim3(NCH, 32), 256, 0, stream>>>(proj, Sinit, Pcum, yloc, yg);
    k_gemm<32, 128><<<dim3(8, 16, KSPLIT2), 256, 0, stream>>>(
        yg, 2048, w_outT, 2048, part2, 1024, 2048 / KSPLIT2);
    k_reduce_out<<<512, 256, 0, stream>>>(part2, x, out);
}

// Round 10
// 143.927 us; speedup vs baseline: 1.1097x; 1.1097x over previous
//
#include <hip/hip_runtime.h>
#include <hip/hip_bf16.h>

typedef unsigned short u16;
typedef float f32x4v __attribute__((ext_vector_type(4)));
typedef short short8 __attribute__((ext_vector_type(8)));

#define TSEQ 512
#define EMB  1024
#define DI   2048
#define NH   32
#define DS   64
#define PROJ 4256
#define PROJP 4352
#define NCH  8    // chunks
#define LCH  64   // chunk length (SSD tile)
#define KSPLIT2 4

#define MFMA16(a, b, c) __builtin_amdgcn_mfma_f32_16x16x32_bf16(a, b, c, 0, 0, 0)

__device__ __forceinline__ u16 f2bf(float f) {
    union { __hip_bfloat16 h; u16 u; } cv;
    cv.h = __float2bfloat16(f);
    return cv.u;
}
__device__ __forceinline__ unsigned pack2(float a, float b) {
    return (unsigned)f2bf(a) | ((unsigned)f2bf(b) << 16);
}
__device__ __forceinline__ float silu(float v) { return v / (1.f + expf(-v)); }

// ---------------- transpose + cast f32 (K x N) -> bf16 (Npad x K), zero-pad n >= N
__device__ __forceinline__ void transpose_tile(
        const float* __restrict__ src, u16* __restrict__ dst,
        int K, int N, int n0, int k0, int tid, float tile[64][68]) {
    const int lr = tid >> 4;
    const int lc = tid & 15;
    #pragma unroll
    for (int ps = 0; ps < 4; ++ps) {
        int r = ps * 16 + lr;
        float4 v;
        if (n0 + lc * 4 + 3 < N) {
            v = *(const float4*)&src[(size_t)(k0 + r) * N + n0 + lc * 4];
        } else {
            float t0 = 0.f, t1 = 0.f, t2 = 0.f, t3 = 0.f;
            int nb = n0 + lc * 4;
            if (nb + 0 < N) t0 = src[(size_t)(k0 + r) * N + nb + 0];
            if (nb + 1 < N) t1 = src[(size_t)(k0 + r) * N + nb + 1];
            if (nb + 2 < N) t2 = src[(size_t)(k0 + r) * N + nb + 2];
            if (nb + 3 < N) t3 = src[(size_t)(k0 + r) * N + nb + 3];
            v = make_float4(t0, t1, t2, t3);
        }
        *(float4*)&tile[r][lc * 4] = v;
    }
    __syncthreads();
    const int kk2 = (tid & 31) * 2;
    const int nr  = tid >> 5;
    #pragma unroll
    for (int ps = 0; ps < 8; ++ps) {
        int n = ps * 8 + nr;
        unsigned o = (unsigned)f2bf(tile[kk2][n]) | ((unsigned)f2bf(tile[kk2 + 1][n]) << 16);
        *(unsigned*)&dst[(size_t)(n0 + n) * K + k0 + kk2] = o;
    }
}

// fused prep: w_in transpose (0..1087), w_out transpose (1088..1599), rmsnorm (1600..2111)
__global__ __launch_bounds__(256) void k_prep(
        const float* __restrict__ w_in, u16* __restrict__ w_inT,
        const float* __restrict__ w_out, u16* __restrict__ w_outT,
        const float* __restrict__ x, const float* __restrict__ scale,
        u16* __restrict__ xnb) {
    __shared__ float tile[64][68];
    const int b = blockIdx.x;
    const int tid = threadIdx.x;
    if (b < 1088) {
        int bx = b % 68, by = b / 68;
        transpose_tile(w_in, w_inT, 1024, PROJ, bx * 64, by * 64, tid, tile);
    } else if (b < 1600) {
        int b2 = b - 1088;
        int bx = b2 % 16, by = b2 / 16;
        transpose_tile(w_out, w_outT, 2048, 1024, bx * 64, by * 64, tid, tile);
    } else {
        int t = b - 1600;
        const float4* xr = (const float4*)(x + (size_t)t * EMB);
        float4 v = xr[tid];
        float ss = v.x * v.x + v.y * v.y + v.z * v.z + v.w * v.w;
        #pragma unroll
        for (int off = 32; off; off >>= 1) ss += __shfl_xor(ss, off);
        if ((tid & 63) == 0) tile[0][tid >> 6] = ss;
        __syncthreads();
        float tot = tile[0][0] + tile[0][1] + tile[0][2] + tile[0][3];
        float inv = rsqrtf(tot * (1.f / EMB) + 1e-6f);
        float4 s = ((const float4*)scale)[tid];
        uint2 o;
        o.x = pack2(v.x * inv * s.x, v.y * inv * s.y);
        o.y = pack2(v.z * inv * s.z, v.w * inv * s.w);
        ((uint2*)xnb)[(size_t)t * 256 + tid] = o;
    }
}

// ---------------- bf16 MFMA GEMM with register prefetch.
template<int BM, int BN>
__global__ __launch_bounds__(256) void k_gemm(
        const u16* __restrict__ A, int lda,
        const u16* __restrict__ BT, int ldb,
        float* __restrict__ C, int ldc, int Kper) {
    constexpr int WM = BM / 2, WN = BN / 2, FM = WM / 16, FN = WN / 16;
    constexpr int NA = BM * 8 / 256, NB = BN * 8 / 256;
    __shared__ __align__(16) u16 Al[BM][72];
    __shared__ __align__(16) u16 Bl[BN][72];
    const int tid = threadIdx.x;
    const int wid = tid >> 6, lane = tid & 63;
    const int wr = wid >> 1, wc = wid & 1;
    const int ar = lane & 15, kg = lane >> 4;
    const int row0 = blockIdx.y * BM, col0 = blockIdx.x * BN;
    const int kbase = blockIdx.z * Kper;
    const int Mtot = gridDim.y * BM;
    float* Cz = C + (size_t)blockIdx.z * Mtot * ldc;

    short8 ra[NA], rb[NB];
    auto load_stage = [&](int k0) {
        #pragma unroll
        for (int j = 0; j < NA; ++j) {
            int idx = tid + j * 256;
            ra[j] = *(const short8*)(A + (size_t)(row0 + (idx >> 3)) * lda + k0 + (idx & 7) * 8);
        }
        #pragma unroll
        for (int j = 0; j < NB; ++j) {
            int idx = tid + j * 256;
            rb[j] = *(const short8*)(BT + (size_t)(col0 + (idx >> 3)) * ldb + k0 + (idx & 7) * 8);
        }
    };
    auto write_stage = [&]() {
        #pragma unroll
        for (int j = 0; j < NA; ++j) {
            int idx = tid + j * 256;
            *(short8*)&Al[idx >> 3][(idx & 7) * 8] = ra[j];
        }
        #pragma unroll
        for (int j = 0; j < NB; ++j) {
            int idx = tid + j * 256;
            *(short8*)&Bl[idx >> 3][(idx & 7) * 8] = rb[j];
        }
    };

    f32x4v acc[FM][FN] = {};
    const int NT = Kper / 64;
    load_stage(kbase);
    for (int kt = 0; kt < NT; ++kt) {
        write_stage();
        __syncthreads();
        if (kt + 1 < NT) load_stage(kbase + (kt + 1) * 64);
        #pragma unroll
        for (int kk = 0; kk < 2; ++kk) {
            short8 af[FM], bf[FN];
            #pragma unroll
            for (int m = 0; m < FM; ++m)
                af[m] = *(const short8*)&Al[wr * WM + m * 16 + ar][kk * 32 + kg * 8];
            #pragma unroll
            for (int n = 0; n < FN; ++n)
                bf[n] = *(const short8*)&Bl[wc * WN + n * 16 + ar][kk * 32 + kg * 8];
            #pragma unroll
            for (int m = 0; m < FM; ++m)
                #pragma unroll
                for (int n = 0; n < FN; ++n)
                    acc[m][n] = MFMA16(af[m], bf[n], acc[m][n]);
        }
        __syncthreads();
    }
    #pragma unroll
    for (int m = 0; m < FM; ++m)
        #pragma unroll
        for (int n = 0; n < FN; ++n)
            #pragma unroll
            for (int j = 0; j < 4; ++j) {
                int row = row0 + wr * WM + m * 16 + kg * 4 + j;
                int col = col0 + wc * WN + n * 16 + ar;
                Cz[(size_t)row * ldc + col] = acc[m][n][j];
            }
}

// ---------------- gemm2 split-K reduce + residual: out = x + sum_z part[z]
__global__ __launch_bounds__(256) void k_reduce_out(
        const float* __restrict__ part, const float* __restrict__ x,
        float* __restrict__ out) {
    int i = blockIdx.x * 256 + threadIdx.x;
    float4 v = ((const float4*)x)[i];
    #pragma unroll
    for (int z = 0; z < KSPLIT2; ++z) {
        float4 p = ((const float4*)part)[(size_t)z * (TSEQ * EMB / 4) + i];
        v.x += p.x; v.y += p.y; v.z += p.z; v.w += p.w;
    }
    ((float4*)out)[i] = v;
}

// ---------------- SSD intra-chunk: per (chunk, head), all-MFMA.
// G = C.B^T (K=n); mask L[t,t'] = exp(la[t]-la[t']) for t'<=t;
// Y_intra = Gm . dtx (K=t'); Sloc[n,p] = sum_t w[t] B[t,n] dtx[t,p] (K=t).
__global__ __launch_bounds__(256) void k_ssd(
        const float* __restrict__ proj, const float* __restrict__ cw,
        const float* __restrict__ cb, const float* __restrict__ A_log,
        const float* __restrict__ dt_bias,
        float* __restrict__ Sloc, float* __restrict__ Lacum,
        float* __restrict__ yloc) {
    const int c = blockIdx.x, h = blockIdx.y;
    const int tid = threadIdx.x;
    const int w = tid >> 6, lane = tid & 63;
    const int ar = lane & 15, kg = lane >> 4;
    __shared__ __align__(16) u16 Bl[64][72];    // B[t][n]
    __shared__ __align__(16) u16 BlTw[64][72];  // w[t]*B[t][n] transposed -> [n][t]
    __shared__ __align__(16) u16 Cl[64][72];    // C[t][n]
    __shared__ __align__(16) u16 XlT[64][72];   // dtx transposed -> [p][t]
    __shared__ __align__(16) u16 Gl[64][72];    // masked G[t][t']
    __shared__ float xt[67][68];
    __shared__ float la[64], dl[64];
    // conv window
    for (int i = tid; i < 67 * 64; i += 256) {
        int r = i >> 6, n = i & 63;
        int tt = c * 64 - 3 + r;
        xt[r][n] = (tt >= 0) ? proj[(size_t)tt * PROJP + DI + h * 64 + n] : 0.f;
    }
    if (tid < 64) {
        float z = proj[(size_t)(c * 64 + tid) * PROJP + 2 * DI + h] + dt_bias[h];
        dl[tid] = (z > 20.f) ? z : log1pf(expf(z));
    }
    __syncthreads();
    if (tid < 64) {
        float cum = 0.f;
        #pragma unroll
        for (int k = 0; k < 64; ++k) if (k <= tid) cum += dl[k];
        float lav = -expf(A_log[h]) * cum;
        la[tid] = lav;
        Lacum[((size_t)(c * 32 + h)) * 64 + tid] = lav;
    }
    __syncthreads();
    const float la63 = la[63];
    for (int i = tid; i < 4096; i += 256) {
        int t = i >> 6, n = i & 63;
        size_t rowoff = (size_t)(c * 64 + t) * PROJP + 2 * DI + NH;
        float bv = proj[rowoff + n];
        float cv = proj[rowoff + DS + n];
        Bl[t][n] = f2bf(bv);
        Cl[t][n] = f2bf(cv);
        BlTw[n][t] = f2bf(bv * expf(la63 - la[t]));
        int ch = h * 64 + n;   // n plays role of channel p here
        float conv = cb[ch]
                   + cw[0 * DI + ch] * xt[t][n]     + cw[1 * DI + ch] * xt[t + 1][n]
                   + cw[2 * DI + ch] * xt[t + 2][n] + cw[3 * DI + ch] * xt[t + 3][n];
        XlT[n][t] = f2bf(dl[t] * silu(conv));
    }
    __syncthreads();
    // G = C . B^T  (wave w: rows t = 16w..16w+15; 4 col tiles; K = n)
    f32x4v accG[4] = {};
    #pragma unroll
    for (int kk = 0; kk < 2; ++kk) {
        short8 af = *(const short8*)&Cl[w * 16 + ar][kk * 32 + kg * 8];
        #pragma unroll
        for (int tc = 0; tc < 4; ++tc) {
            short8 bf = *(const short8*)&Bl[tc * 16 + ar][kk * 32 + kg * 8];
            accG[tc] = MFMA16(af, bf, accG[tc]);
        }
    }
    #pragma unroll
    for (int tc = 0; tc < 4; ++tc) {
        int tp = tc * 16 + ar;           // t' (col)
        #pragma unroll
        for (int j = 0; j < 4; ++j) {
            int t = w * 16 + kg * 4 + j; // t (row)
            float v = (tp <= t) ? accG[tc][j] * expf(la[t] - la[tp]) : 0.f;
            Gl[t][tp] = f2bf(v);
        }
    }
    __syncthreads();
    // Y_intra = Gm . dtx  (A=Gl[t][t'], B=XlT[p][t'], K=t')
    // Sloc    = (wB)^T . dtx^T (A=BlTw[n][t], B=XlT[p][t], K=t)
    f32x4v accY[4] = {}, accS[4] = {};
    #pragma unroll
    for (int kk = 0; kk < 2; ++kk) {
        short8 ag = *(const short8*)&Gl[w * 16 + ar][kk * 32 + kg * 8];
        short8 ab = *(const short8*)&BlTw[w * 16 + ar][kk * 32 + kg * 8];
        #pragma unroll
        for (int tc = 0; tc < 4; ++tc) {
            short8 bx = *(const short8*)&XlT[tc * 16 + ar][kk * 32 + kg * 8];
            accY[tc] = MFMA16(ag, bx, accY[tc]);
            accS[tc] = MFMA16(ab, bx, accS[tc]);
        }
    }
    float* slc = Sloc + ((size_t)(c * 32 + h)) * 4096;
    #pragma unroll
    for (int tc = 0; tc < 4; ++tc) {
        int p = tc * 16 + ar;
        #pragma unroll
        for (int j = 0; j < 4; ++j) {
            int r = w * 16 + kg * 4 + j;   // t for Y; n for Sloc
            yloc[(size_t)(c * 64 + r) * DI + h * 64 + p] = accY[tc][j];
            slc[p * 64 + r] = accS[tc][j];  // Sloc[p][n]
        }
    }
}

// ---------------- inter-chunk recurrence (tiny, streaming)
__global__ __launch_bounds__(256) void k_scan2(
        const float* __restrict__ Sloc, const float* __restrict__ Lacum,
        float* __restrict__ Sinit) {
    int gid = blockIdx.x * 256 + threadIdx.x;   // < 32*4096
    int h = gid >> 12, rem = gid & 4095;
    float s = 0.f;
    #pragma unroll
    for (int cc = 0; cc < NCH; ++cc) {
        size_t o = (size_t)(cc * 32 + h) * 4096 + rem;
        Sinit[o] = s;
        float ptot = expf(Lacum[((size_t)(cc * 32 + h)) * 64 + 63]);
        s = ptot * s + Sloc[o];
    }
}

// ---------------- correction (MFMA): Yc[t,p] = exp(la[t]) * sum_n C[t,n] Sinit[p,n];
// y = yloc + Yc; yg = f2bf(y * silu(gate)).
__global__ __launch_bounds__(256) void k_corr2(
        const float* __restrict__ proj, const float* __restrict__ Sinit,
        const float* __restrict__ Lacum, const float* __restrict__ yloc,
        u16* __restrict__ yg) {
    const int c = blockIdx.x, h = blockIdx.y;
    const int tid = threadIdx.x;
    const int w = tid >> 6, lane = tid & 63;
    const int ar = lane & 15, kg = lane >> 4;
    __shared__ __align__(16) u16 Cl[64][72];  // C[t][n]
    __shared__ __align__(16) u16 Sl[64][72];  // Sinit[p][n]
    __shared__ float la[64];
    const float* sic = Sinit + ((size_t)(c * 32 + h)) * 4096;
    for (int i = tid; i < 4096; i += 256) {
        int t = i >> 6, n = i & 63;
        Cl[t][n] = f2bf(proj[(size_t)(c * 64 + t) * PROJP + 2 * DI + NH + DS + n]);
        Sl[t][n] = f2bf(sic[i]);   // row = p, col = n
    }
    if (tid < 64) la[tid] = Lacum[((size_t)(c * 32 + h)) * 64 + tid];
    __syncthreads();
    f32x4v acc[4] = {};
    #pragma unroll
    for (int kk = 0; kk < 2; ++kk) {
        short8 ac = *(const short8*)&Cl[w * 16 + ar][kk * 32 + kg * 8];
        #pragma unroll
        for (int tc = 0; tc < 4; ++tc) {
            short8 bs = *(const short8*)&Sl[tc * 16 + ar][kk * 32 + kg * 8];
            acc[tc] = MFMA16(ac, bs, acc[tc]);
        }
    }
    #pragma unroll
    for (int tc = 0; tc < 4; ++tc) {
        int p = tc * 16 + ar;
        #pragma unroll
        for (int j = 0; j < 4; ++j) {
            int t = w * 16 + kg * 4 + j;
            float y = yloc[(size_t)(c * 64 + t) * DI + h * 64 + p]
                    + expf(la[t]) * acc[tc][j];
            float g = proj[(size_t)(c * 64 + t) * PROJP + h * 64 + p];
            yg[(size_t)(c * 64 + t) * DI + h * 64 + p] = f2bf(y * silu(g));
        }
    }
}

extern "C" void kernel_launch(void* const* d_in, const int* in_sizes, int n_in,
                              void* d_out, int out_size, void* d_ws, size_t ws_size,
                              hipStream_t stream) {
    (void)in_sizes; (void)n_in; (void)out_size; (void)ws_size;
    const float* x       = (const float*)d_in[0];
    const float* nscale  = (const float*)d_in[1];
    const float* w_in    = (const float*)d_in[2];
    const float* conv_w  = (const float*)d_in[3];
    const float* conv_b  = (const float*)d_in[4];
    const float* A_log   = (const float*)d_in[5];
    const float* dt_bias = (const float*)d_in[6];
    const float* w_out   = (const float*)d_in[7];
    float* out = (float*)d_out;

    char* wsp = (char*)d_ws;
    auto alloc = [&](size_t bytes) {
        char* ptr = wsp;
        wsp += (bytes + 255) & ~(size_t)255;
        return ptr;
    };
    u16*   w_inT  = (u16*)  alloc((size_t)PROJP * 1024 * 2);
    u16*   w_outT = (u16*)  alloc((size_t)1024 * 2048 * 2);
    u16*   xnb    = (u16*)  alloc((size_t)512 * 1024 * 2);
    float* proj   = (float*)alloc((size_t)512 * PROJP * 4);
    float* Lacum  = (float*)alloc((size_t)NCH * 32 * 64 * 4);
    float* Sloc   = (float*)alloc((size_t)NCH * 32 * 4096 * 4);
    float* Sinit  = (float*)alloc((size_t)NCH * 32 * 4096 * 4);
    float* yloc   = (float*)alloc((size_t)512 * 2048 * 4);
    u16*   yg     = (u16*)  alloc((size_t)512 * 2048 * 2);
    float* part2  = (float*)alloc((size_t)KSPLIT2 * 512 * 1024 * 4);

    k_prep<<<2112, 256, 0, stream>>>(w_in, w_inT, w_out, w_outT, x, nscale, xnb);
    k_gemm<32, 128><<<dim3(34, 16, 1), 256, 0, stream>>>(
        xnb, 1024, w_inT, 1024, proj, PROJP, 1024);
    k_ssd<<<dim3(NCH, 32), 256, 0, stream>>>(
        proj, conv_w, conv_b, A_log, dt_bias, Sloc, Lacum, yloc);
    k_scan2<<<512, 256, 0, stream>>>(Sloc, Lacum, Sinit);
    k_corr2<<<dim3(NCH, 32), 256, 0, stream>>>(proj, Sinit, Lacum, yloc, yg);
    k_gemm<32, 128><<<dim3(8, 16, KSPLIT2), 256, 0, stream>>>(
        yg, 2048, w_outT, 2048, part2, 1024, 2048 / KSPLIT2);
    k_reduce_out<<<512, 256, 0, stream>>>(part2, x, out);
}